// Round 6
// baseline (124.396 us; speedup 1.0000x reference)
//
#include <hip/hip_runtime.h>
#include <hip/hip_bf16.h>

// Shapes (fixed by setup_inputs): bs=8, v=2048, n=20, inc=64, outc=128, sup=2
#define BS    8
#define V     2048
#define NNB   20
#define INC   64
#define OUTC  128
#define SUP   2
#define NCOL  ((SUP + 1) * OUTC)   // 384
#define SCOL  (SUP * OUTC)         // 256
#define ROWS  (BS * V)             // 16384

using bf16x8 = __bf16 __attribute__((ext_vector_type(8)));
using bf16x4 = __bf16 __attribute__((ext_vector_type(4)));
using f32x4  = float  __attribute__((ext_vector_type(4)));
using f32x2  = float  __attribute__((ext_vector_type(2)));
using i32x4  = int    __attribute__((ext_vector_type(4)));
using u16x4  = unsigned short __attribute__((ext_vector_type(4)));

#if __has_builtin(__builtin_elementwise_fma)
static __device__ inline f32x2 efma(f32x2 a, f32x2 b, f32x2 c) { return __builtin_elementwise_fma(a, b, c); }
#else
static __device__ inline f32x2 efma(f32x2 a, f32x2 b, f32x2 c) {
    f32x2 r; r[0] = fmaf(a[0], b[0], c[0]); r[1] = fmaf(a[1], b[1], c[1]); return r;
}
#endif
#if __has_builtin(__builtin_elementwise_max)
static __device__ inline f32x2 emax(f32x2 a, f32x2 b) { return __builtin_elementwise_max(a, b); }
#else
static __device__ inline f32x2 emax(f32x2 a, f32x2 b) {
    f32x2 r; r[0] = fmaxf(a[0], b[0]); r[1] = fmaxf(a[1], b[1]); return r;
}
#endif

static __device__ inline bf16x8 cvt8(f32x4 lo, f32x4 hi) {
    bf16x8 r;
    r[0] = (__bf16)lo[0]; r[1] = (__bf16)lo[1]; r[2] = (__bf16)lo[2]; r[3] = (__bf16)lo[3];
    r[4] = (__bf16)hi[0]; r[5] = (__bf16)hi[1]; r[6] = (__bf16)hi[2]; r[7] = (__bf16)hi[3];
    return r;
}

// bf16 (raw u16) -> f32: value = bits << 16
static __device__ inline float b2f(unsigned short u) {
    union { unsigned int i; float f; } c; c.i = ((unsigned int)u) << 16; return c.f;
}

// ---------------------------------------------------------------------------
// K0: prep — WTb bf16 [384][64], Wm1b bf16 [128][128], w2 = Wm2 @ u,
//     u[k] = relu(dw[k]) + relu(dw[128+k])  (valid since dmax >= 0).
// ---------------------------------------------------------------------------
__global__ __launch_bounds__(256) void k_prep(const float* __restrict__ W,
                                              const float* __restrict__ Wm,
                                              const float* __restrict__ dw,
                                              __bf16* __restrict__ WTb,
                                              __bf16* __restrict__ Wm1b,
                                              float* __restrict__ w2) {
    const int b = blockIdx.x;
    if (b < 96) {                       // W [64][384] -> WTb [384][64], coalesced writes
        const int idx = b * 256 + threadIdx.x;      // < 24576
        const int c = idx >> 6, k = idx & 63;
        WTb[idx] = (__bf16)W[k * NCOL + c];
    } else if (b < 160) {               // Wm[:, :128] -> bf16 [o][k]
        const int idx = (b - 96) * 256 + threadIdx.x;   // < 16384
        const int o = idx >> 7, k = idx & 127;
        Wm1b[idx] = (__bf16)Wm[o * SCOL + k];
    } else {                            // u + w2
        __shared__ float u[OUTC];
        const int t = threadIdx.x;
        if (t < OUTC) u[t] = fmaxf(dw[t], 0.f) + fmaxf(dw[OUTC + t], 0.f);
        __syncthreads();
        if (t < OUTC) {
            float s = 0.f;
            for (int k = 0; k < OUTC; ++k) s = fmaf(Wm[t * SCOL + OUTC + k], u[k], s);
            w2[t] = s;
        }
    }
}

// ---------------------------------------------------------------------------
// K1: feat = fm @ W + bias (MFMA bf16). Block = 4 waves, 32 rows x 384 cols.
// Wave w: cols w*96..+95 (6 tiles), 2 row-sets of 16 sharing each B fragment.
// center -> f32, support -> bf16 (consumed by k_neigh gathers).
// ---------------------------------------------------------------------------
__global__ __launch_bounds__(256) void k_feat(const float* __restrict__ fm,
                                              const __bf16* __restrict__ WTb,
                                              const float* __restrict__ bias,
                                              float* __restrict__ center,
                                              __bf16* __restrict__ supb) {
    const int row0 = blockIdx.x * 32;
    const int wid = threadIdx.x >> 6, lane = threadIdx.x & 63;
    const int ln = lane & 15, lg = lane >> 4;
    const int cbase = wid * 96;

    bf16x8 a[2][2];
#pragma unroll
    for (int rs = 0; rs < 2; ++rs) {
        const float* ap = fm + (size_t)(row0 + rs * 16 + ln) * INC + lg * 8;
        a[rs][0] = cvt8(*(const f32x4*)(ap +  0), *(const f32x4*)(ap +  4));
        a[rs][1] = cvt8(*(const f32x4*)(ap + 32), *(const f32x4*)(ap + 36));
    }

    f32x4 acc[2][6];
#pragma unroll
    for (int t = 0; t < 6; ++t) {
        const float bb = bias[cbase + t * 16 + ln];
        acc[0][t] = (f32x4){bb, bb, bb, bb};
        acc[1][t] = acc[0][t];
    }

    const __bf16* bp = WTb + (size_t)(cbase + ln) * INC + lg * 8;
#pragma unroll
    for (int t = 0; t < 6; ++t) {
        const bf16x8 b0 = *(const bf16x8*)(bp + t * 16 * INC);
        const bf16x8 b1 = *(const bf16x8*)(bp + t * 16 * INC + 32);
        acc[0][t] = __builtin_amdgcn_mfma_f32_16x16x32_bf16(a[0][0], b0, acc[0][t], 0, 0, 0);
        acc[0][t] = __builtin_amdgcn_mfma_f32_16x16x32_bf16(a[0][1], b1, acc[0][t], 0, 0, 0);
        acc[1][t] = __builtin_amdgcn_mfma_f32_16x16x32_bf16(a[1][0], b0, acc[1][t], 0, 0, 0);
        acc[1][t] = __builtin_amdgcn_mfma_f32_16x16x32_bf16(a[1][1], b1, acc[1][t], 0, 0, 0);
    }

    // C: col = lane&15, row = (lane>>4)*4 + r
#pragma unroll
    for (int rs = 0; rs < 2; ++rs) {
        const int r0 = row0 + rs * 16 + lg * 4;
#pragma unroll
        for (int t = 0; t < 6; ++t) {
            const int col = cbase + t * 16 + ln;
            if (col < OUTC) {
#pragma unroll
                for (int r = 0; r < 4; ++r)
                    center[(size_t)(r0 + r) * OUTC + col] = acc[rs][t][r];
            } else {
                const int sc = col - OUTC;
#pragma unroll
                for (int r = 0; r < 4; ++r)
                    supb[(size_t)(r0 + r) * SCOL + sc] = (__bf16)acc[rs][t][r];
            }
        }
    }
}

// ---------------------------------------------------------------------------
// K2: neighbor phase. 2 vertices/wave (32 lanes each); lane sl owns cols
// sl*4..+3 of each support half. Batch verts staged in LDS (padded float4,
// 32 KB) so the per-neighbor chain is ds_read (not global gather).
// Support gathers bf16x4 (8B), issued 10-at-a-time in 5-neighbor chunks.
// __launch_bounds__(256,4): 128 VGPR budget for load-hoisting.
// batch = bid&7 XCD swizzle (batch's support slice sticks to one XCD L2).
// ---------------------------------------------------------------------------
__global__ __launch_bounds__(256, 4) void k_neigh(const int*   __restrict__ nbr,
                                                  const float* __restrict__ verts,
                                                  const float* __restrict__ dirs,
                                                  const float* __restrict__ center,
                                                  const __bf16* __restrict__ supb,
                                                  __bf16* __restrict__ Xb,
                                                  float* __restrict__ dmaxv) {
    const int bid   = blockIdx.x;
    const int batch = bid & 7;
    const int chunk = bid >> 3;
    const int wid   = threadIdx.x >> 6;
    const int lane  = threadIdx.x & 63;
    const int half  = lane >> 5;
    const int sl    = lane & 31;
    const int u     = chunk * 8 + wid * 2 + half;
    const int bV    = batch * V;
    const int row   = bV + u;
    const int c0    = sl * 4;

    __shared__ float vlds[V][4];          // 32 KB

    // coalesced stage of this batch's vertices (6144 floats)
    for (int i = threadIdx.x; i < V * 3; i += 256) {
        const int vv = i / 3, cc = i - vv * 3;
        vlds[vv][cc] = verts[(size_t)bV * 3 + i];
    }

    // normalized spatial directions: half A cols c0..+3, half B cols 128+c0..+3
    f32x4 A0 = *(const f32x4*)(dirs +            c0);
    f32x4 A1 = *(const f32x4*)(dirs + SCOL +     c0);
    f32x4 A2 = *(const f32x4*)(dirs + 2*SCOL +   c0);
    f32x4 B0 = *(const f32x4*)(dirs +            OUTC + c0);
    f32x4 B1 = *(const f32x4*)(dirs + SCOL +     OUTC + c0);
    f32x4 B2 = *(const f32x4*)(dirs + 2*SCOL +   OUTC + c0);
#pragma unroll
    for (int j = 0; j < 4; ++j) {
        float inv = __builtin_amdgcn_rsqf(fmaxf(fmaf(A0[j], A0[j], fmaf(A1[j], A1[j], A2[j]*A2[j])), 1e-24f));
        A0[j] *= inv; A1[j] *= inv; A2[j] *= inv;
        inv = __builtin_amdgcn_rsqf(fmaxf(fmaf(B0[j], B0[j], fmaf(B1[j], B1[j], B2[j]*B2[j])), 1e-24f));
        B0[j] *= inv; B1[j] *= inv; B2[j] *= inv;
    }
    const f32x2 ax0 = {A0[0], A0[1]}, ax1 = {A0[2], A0[3]};
    const f32x2 ay0 = {A1[0], A1[1]}, ay1 = {A1[2], A1[3]};
    const f32x2 az0 = {A2[0], A2[1]}, az1 = {A2[2], A2[3]};
    const f32x2 bx0 = {B0[0], B0[1]}, bx1 = {B0[2], B0[3]};
    const f32x2 by0 = {B1[0], B1[1]}, by1 = {B1[2], B1[3]};
    const f32x2 bz0 = {B2[0], B2[1]}, bz1 = {B2[2], B2[3]};
    const f32x2 zero = {0.f, 0.f};

    // all 20 neighbor indices
    int gs[NNB];
    {
        const i32x4* np4 = reinterpret_cast<const i32x4*>(nbr + (size_t)row * NNB);
#pragma unroll
        for (int t = 0; t < 5; ++t) {
            const i32x4 g4 = np4[t];
            gs[t*4+0] = g4[0]; gs[t*4+1] = g4[1]; gs[t*4+2] = g4[2]; gs[t*4+3] = g4[3];
        }
    }

    __syncthreads();   // vlds ready

    const float vx = vlds[u][0], vy = vlds[u][1], vz = vlds[u][2];

    f32x2 mA0 = {-INFINITY, -INFINITY}, mA1 = mA0, mB0 = mA0, mB1 = mA0;
    float d2max = 0.f;
    const __bf16* supBase = supb + (size_t)bV * SCOL + c0;

#pragma unroll
    for (int t = 0; t < 4; ++t) {
        // phase A: issue 10 support gathers + 5 LDS vertex reads
        u16x4 s0r[5], s1r[5];
        f32x4 vl[5];
#pragma unroll
        for (int q = 0; q < 5; ++q) {
            const int g = gs[t * 5 + q];
            const __bf16* sg = supBase + (size_t)g * SCOL;
            s0r[q] = *(const u16x4*)(sg);
            s1r[q] = *(const u16x4*)(sg + OUTC);
            vl[q]  = *(const f32x4*)&vlds[g][0];
        }
        // phase B: math
#pragma unroll
        for (int q = 0; q < 5; ++q) {
            const float dx = vl[q][0] - vx, dy = vl[q][1] - vy, dz = vl[q][2] - vz;
            const float d2 = fmaf(dx, dx, fmaf(dy, dy, dz * dz));
            d2max = fmaxf(d2max, d2);
            const float inv = __builtin_amdgcn_rsqf(fmaxf(d2, 1e-24f));  // == 1/max(dist,1e-12)
            const f32x2 nX = {dx * inv, dx * inv};
            const f32x2 nY = {dy * inv, dy * inv};
            const f32x2 nZ = {dz * inv, dz * inv};

            const f32x2 s0lo = {b2f(s0r[q][0]), b2f(s0r[q][1])};
            const f32x2 s0hi = {b2f(s0r[q][2]), b2f(s0r[q][3])};
            const f32x2 s1lo = {b2f(s1r[q][0]), b2f(s1r[q][1])};
            const f32x2 s1hi = {b2f(s1r[q][2]), b2f(s1r[q][3])};

            const f32x2 tA0 = emax(efma(nZ, az0, efma(nY, ay0, nX * ax0)), zero);
            const f32x2 tA1 = emax(efma(nZ, az1, efma(nY, ay1, nX * ax1)), zero);
            const f32x2 tB0 = emax(efma(nZ, bz0, efma(nY, by0, nX * bx0)), zero);
            const f32x2 tB1 = emax(efma(nZ, bz1, efma(nY, by1, nX * bx1)), zero);
            mA0 = emax(mA0, tA0 * s0lo);
            mA1 = emax(mA1, tA1 * s0hi);
            mB0 = emax(mB0, tB0 * s1lo);
            mB1 = emax(mB1, tB1 * s1hi);
        }
    }

    const f32x4 cc = *(const f32x4*)(center + (size_t)row * OUTC + c0);
    const f32x2 f01 = (f32x2){cc[0], cc[1]} + mA0 + mB0;
    const f32x2 f23 = (f32x2){cc[2], cc[3]} + mA1 + mB1;
    bf16x4 fx;
    fx[0] = (__bf16)f01[0]; fx[1] = (__bf16)f01[1];
    fx[2] = (__bf16)f23[0]; fx[3] = (__bf16)f23[1];
    *(bf16x4*)(Xb + (size_t)row * OUTC + c0) = fx;
    if (sl == 0) dmaxv[row] = sqrtf(d2max);
}

// ---------------------------------------------------------------------------
// K3: out = Xb @ Wm1b^T + dmax*w2 + mlp_b (MFMA bf16, K=128).
// Block = 4 waves: wave w -> rows blk*32 + (w>>1)*16, cols (w&1)*64 (4 tiles).
// ---------------------------------------------------------------------------
__global__ __launch_bounds__(256) void k_out(const __bf16* __restrict__ Xb,
                                             const __bf16* __restrict__ Wm1b,
                                             const float* __restrict__ dmaxv,
                                             const float* __restrict__ w2,
                                             const float* __restrict__ mb,
                                             float* __restrict__ out) {
    const int wid = threadIdx.x >> 6, lane = threadIdx.x & 63;
    const int ln = lane & 15, lg = lane >> 4;
    const int row0 = blockIdx.x * 32 + (wid >> 1) * 16;
    const int cb = (wid & 1) * 64;

    const __bf16* ap = Xb + (size_t)(row0 + ln) * OUTC + lg * 8;
    bf16x8 a[4];
#pragma unroll
    for (int kf = 0; kf < 4; ++kf) a[kf] = *(const bf16x8*)(ap + kf * 32);

    f32x4 acc[4];
#pragma unroll
    for (int t = 0; t < 4; ++t) acc[t] = (f32x4)0.f;

    const __bf16* bp = Wm1b + (size_t)(cb + ln) * OUTC + lg * 8;
#pragma unroll
    for (int t = 0; t < 4; ++t) {
#pragma unroll
        for (int kf = 0; kf < 4; ++kf) {
            const bf16x8 b = *(const bf16x8*)(bp + t * 16 * OUTC + kf * 32);
            acc[t] = __builtin_amdgcn_mfma_f32_16x16x32_bf16(a[kf], b, acc[t], 0, 0, 0);
        }
    }

    float dm[4];
#pragma unroll
    for (int r = 0; r < 4; ++r) dm[r] = dmaxv[row0 + lg * 4 + r];

#pragma unroll
    for (int t = 0; t < 4; ++t) {
        const int col = cb + t * 16 + ln;
        const float w2c = w2[col];
        const float bb = mb[col];
#pragma unroll
        for (int r = 0; r < 4; ++r)
            out[(size_t)(row0 + lg * 4 + r) * OUTC + col] = fmaf(dm[r], w2c, acc[t][r] + bb);
    }
}

// ---------------------------------------------------------------------------
extern "C" void kernel_launch(void* const* d_in, const int* in_sizes, int n_in,
                              void* d_out, int out_size, void* d_ws, size_t ws_size,
                              hipStream_t stream) {
    const int*   nbr   = (const int*)  d_in[0];
    const float* verts = (const float*)d_in[1];
    const float* fm    = (const float*)d_in[2];
    const float* W     = (const float*)d_in[3];
    const float* bias  = (const float*)d_in[4];
    const float* dirs  = (const float*)d_in[5];
    const float* dw    = (const float*)d_in[6];
    const float* Wm    = (const float*)d_in[7];
    const float* mb    = (const float*)d_in[8];
    float* out = (float*)d_out;

    // workspace layout (all 16B-aligned)
    float*  center  = (float*)d_ws;                               // 16384*128 f32
    __bf16* supb    = (__bf16*)(center + (size_t)ROWS * OUTC);    // 16384*256 bf16
    __bf16* Xb      = supb + (size_t)ROWS * SCOL;                 // 16384*128 bf16
    float*  dmaxv   = (float*)(Xb + (size_t)ROWS * OUTC);         // 16384 f32
    __bf16* WTb     = (__bf16*)(dmaxv + ROWS);                    // 384*64 bf16
    __bf16* Wm1b    = WTb + NCOL * INC;                           // 128*128 bf16
    float*  w2      = (float*)(Wm1b + OUTC * OUTC);               // 128 f32

    k_prep <<<161,        256, 0, stream>>>(W, Wm, dw, WTb, Wm1b, w2);
    k_feat <<<ROWS / 32,  256, 0, stream>>>(fm, WTb, bias, center, supb);
    k_neigh<<<ROWS / 8,   256, 0, stream>>>(nbr, verts, dirs, center, supb, Xb, dmaxv);
    k_out  <<<ROWS / 32,  256, 0, stream>>>(Xb, Wm1b, dmaxv, w2, mb, out);
}

// Round 9
// 117.261 us; speedup vs baseline: 1.0609x; 1.0609x over previous
//
#include <hip/hip_runtime.h>
#include <hip/hip_bf16.h>

// Shapes (fixed by setup_inputs): bs=8, v=2048, n=20, inc=64, outc=128, sup=2
#define BS    8
#define V     2048
#define NNB   20
#define INC   64
#define OUTC  128
#define SUP   2
#define NCOL  ((SUP + 1) * OUTC)   // 384
#define SCOL  (SUP * OUTC)         // 256
#define ROWS  (BS * V)             // 16384
#define XPAD  136                  // 128 + 8 bf16 pad -> 2-way-free b128 reads

using bf16x8 = __bf16 __attribute__((ext_vector_type(8)));
using bf16x4 = __bf16 __attribute__((ext_vector_type(4)));
using f32x4  = float  __attribute__((ext_vector_type(4)));
using f32x2  = float  __attribute__((ext_vector_type(2)));
using i32x4  = int    __attribute__((ext_vector_type(4)));
using u16x4  = unsigned short __attribute__((ext_vector_type(4)));

#if __has_builtin(__builtin_elementwise_fma)
static __device__ inline f32x2 efma(f32x2 a, f32x2 b, f32x2 c) { return __builtin_elementwise_fma(a, b, c); }
#else
static __device__ inline f32x2 efma(f32x2 a, f32x2 b, f32x2 c) {
    f32x2 r; r[0] = fmaf(a[0], b[0], c[0]); r[1] = fmaf(a[1], b[1], c[1]); return r;
}
#endif
#if __has_builtin(__builtin_elementwise_max)
static __device__ inline f32x2 emax(f32x2 a, f32x2 b) { return __builtin_elementwise_max(a, b); }
#else
static __device__ inline f32x2 emax(f32x2 a, f32x2 b) {
    f32x2 r; r[0] = fmaxf(a[0], b[0]); r[1] = fmaxf(a[1], b[1]); return r;
}
#endif

static __device__ inline bf16x8 cvt8(f32x4 lo, f32x4 hi) {
    bf16x8 r;
    r[0] = (__bf16)lo[0]; r[1] = (__bf16)lo[1]; r[2] = (__bf16)lo[2]; r[3] = (__bf16)lo[3];
    r[4] = (__bf16)hi[0]; r[5] = (__bf16)hi[1]; r[6] = (__bf16)hi[2]; r[7] = (__bf16)hi[3];
    return r;
}

// bf16 (raw u16) -> f32: value = bits << 16
static __device__ inline float b2f(unsigned short u) {
    union { unsigned int i; float f; } c; c.i = ((unsigned int)u) << 16; return c.f;
}

// ---------------------------------------------------------------------------
// K0: prep — WTb bf16 [384][64], Wm1b bf16 [128][128], w2 = Wm2 @ u,
//     u[k] = relu(dw[k]) + relu(dw[128+k])  (valid since dmax >= 0).
// ---------------------------------------------------------------------------
__global__ __launch_bounds__(256) void k_prep(const float* __restrict__ W,
                                              const float* __restrict__ Wm,
                                              const float* __restrict__ dw,
                                              __bf16* __restrict__ WTb,
                                              __bf16* __restrict__ Wm1b,
                                              float* __restrict__ w2) {
    const int b = blockIdx.x;
    if (b < 96) {                       // W [64][384] -> WTb [384][64], coalesced writes
        const int idx = b * 256 + threadIdx.x;      // < 24576
        const int c = idx >> 6, k = idx & 63;
        WTb[idx] = (__bf16)W[k * NCOL + c];
    } else if (b < 160) {               // Wm[:, :128] -> bf16 [o][k]
        const int idx = (b - 96) * 256 + threadIdx.x;   // < 16384
        const int o = idx >> 7, k = idx & 127;
        Wm1b[idx] = (__bf16)Wm[o * SCOL + k];
    } else {                            // u + w2
        __shared__ float u[OUTC];
        const int t = threadIdx.x;
        if (t < OUTC) u[t] = fmaxf(dw[t], 0.f) + fmaxf(dw[OUTC + t], 0.f);
        __syncthreads();
        if (t < OUTC) {
            float s = 0.f;
            for (int k = 0; k < OUTC; ++k) s = fmaf(Wm[t * SCOL + OUTC + k], u[k], s);
            w2[t] = s;
        }
    }
}

// ---------------------------------------------------------------------------
// K1: feat = fm @ W + bias (MFMA bf16). Block = 4 waves, 32 rows x 384 cols.
// center -> f32, support -> bf16 (consumed by k_no gathers).
// ---------------------------------------------------------------------------
__global__ __launch_bounds__(256) void k_feat(const float* __restrict__ fm,
                                              const __bf16* __restrict__ WTb,
                                              const float* __restrict__ bias,
                                              float* __restrict__ center,
                                              __bf16* __restrict__ supb) {
    const int row0 = blockIdx.x * 32;
    const int wid = threadIdx.x >> 6, lane = threadIdx.x & 63;
    const int ln = lane & 15, lg = lane >> 4;
    const int cbase = wid * 96;

    bf16x8 a[2][2];
#pragma unroll
    for (int rs = 0; rs < 2; ++rs) {
        const float* ap = fm + (size_t)(row0 + rs * 16 + ln) * INC + lg * 8;
        a[rs][0] = cvt8(*(const f32x4*)(ap +  0), *(const f32x4*)(ap +  4));
        a[rs][1] = cvt8(*(const f32x4*)(ap + 32), *(const f32x4*)(ap + 36));
    }

    f32x4 acc[2][6];
#pragma unroll
    for (int t = 0; t < 6; ++t) {
        const float bb = bias[cbase + t * 16 + ln];
        acc[0][t] = (f32x4){bb, bb, bb, bb};
        acc[1][t] = acc[0][t];
    }

    const __bf16* bp = WTb + (size_t)(cbase + ln) * INC + lg * 8;
#pragma unroll
    for (int t = 0; t < 6; ++t) {
        const bf16x8 b0 = *(const bf16x8*)(bp + t * 16 * INC);
        const bf16x8 b1 = *(const bf16x8*)(bp + t * 16 * INC + 32);
        acc[0][t] = __builtin_amdgcn_mfma_f32_16x16x32_bf16(a[0][0], b0, acc[0][t], 0, 0, 0);
        acc[0][t] = __builtin_amdgcn_mfma_f32_16x16x32_bf16(a[0][1], b1, acc[0][t], 0, 0, 0);
        acc[1][t] = __builtin_amdgcn_mfma_f32_16x16x32_bf16(a[1][0], b0, acc[1][t], 0, 0, 0);
        acc[1][t] = __builtin_amdgcn_mfma_f32_16x16x32_bf16(a[1][1], b1, acc[1][t], 0, 0, 0);
    }

    // C: col = lane&15, row = (lane>>4)*4 + r
#pragma unroll
    for (int rs = 0; rs < 2; ++rs) {
        const int r0 = row0 + rs * 16 + lg * 4;
#pragma unroll
        for (int t = 0; t < 6; ++t) {
            const int col = cbase + t * 16 + ln;
            if (col < OUTC) {
#pragma unroll
                for (int r = 0; r < 4; ++r)
                    center[(size_t)(r0 + r) * OUTC + col] = acc[rs][t][r];
            } else {
                const int sc = col - OUTC;
#pragma unroll
                for (int r = 0; r < 4; ++r)
                    supb[(size_t)(r0 + r) * SCOL + sc] = (__bf16)acc[rs][t][r];
            }
        }
    }
}

// ---------------------------------------------------------------------------
// K2 (merged neigh+out): block = 16 vertices, grid 1024 (4 blk/CU).
// Phase N: 2 vertices/wave-pass x 2 passes; lane sl owns cols sl*4..+3 of
//   each support half; fuse (bf16) -> LDS Xl[16][136], dmax -> LDS dl[16].
// Phase G: out = Xl @ Wm1b^T + dmax*w2 + mb, A-frags via ds_read_b128
//   (XPAD=136 -> 2-way bank alias only, free).
// batch = bid&7 XCD swizzle (batch's support slice sticks to one XCD L2).
// ---------------------------------------------------------------------------
__global__ __launch_bounds__(256, 4) void k_no(const int*   __restrict__ nbr,
                                               const float* __restrict__ verts,
                                               const float* __restrict__ dirs,
                                               const float* __restrict__ center,
                                               const __bf16* __restrict__ supb,
                                               const __bf16* __restrict__ Wm1b,
                                               const float* __restrict__ w2,
                                               const float* __restrict__ mb,
                                               float* __restrict__ out) {
    const int bid   = blockIdx.x;
    const int batch = bid & 7;
    const int chunk = bid >> 3;            // 0..127
    const int u0    = chunk * 16;
    const int bV    = batch * V;
    const int tid   = threadIdx.x;
    const int wid   = tid >> 6;
    const int lane  = tid & 63;
    const int half  = lane >> 5;
    const int sl    = lane & 31;
    const int c0    = sl * 4;
    const int ln    = lane & 15, lg = lane >> 4;

    __shared__ __bf16 Xl[16][XPAD];        // 4.25 KB
    __shared__ float  dl[16];

    // ---- normalized spatial directions (once per thread, reused 4 vertices)
    f32x4 A0 = *(const f32x4*)(dirs +            c0);
    f32x4 A1 = *(const f32x4*)(dirs + SCOL +     c0);
    f32x4 A2 = *(const f32x4*)(dirs + 2*SCOL +   c0);
    f32x4 B0 = *(const f32x4*)(dirs +            OUTC + c0);
    f32x4 B1 = *(const f32x4*)(dirs + SCOL +     OUTC + c0);
    f32x4 B2 = *(const f32x4*)(dirs + 2*SCOL +   OUTC + c0);
#pragma unroll
    for (int j = 0; j < 4; ++j) {
        float inv = __builtin_amdgcn_rsqf(fmaxf(fmaf(A0[j], A0[j], fmaf(A1[j], A1[j], A2[j]*A2[j])), 1e-24f));
        A0[j] *= inv; A1[j] *= inv; A2[j] *= inv;
        inv = __builtin_amdgcn_rsqf(fmaxf(fmaf(B0[j], B0[j], fmaf(B1[j], B1[j], B2[j]*B2[j])), 1e-24f));
        B0[j] *= inv; B1[j] *= inv; B2[j] *= inv;
    }
    const f32x2 ax0 = {A0[0], A0[1]}, ax1 = {A0[2], A0[3]};
    const f32x2 ay0 = {A1[0], A1[1]}, ay1 = {A1[2], A1[3]};
    const f32x2 az0 = {A2[0], A2[1]}, az1 = {A2[2], A2[3]};
    const f32x2 bx0 = {B0[0], B0[1]}, bx1 = {B0[2], B0[3]};
    const f32x2 by0 = {B1[0], B1[1]}, by1 = {B1[2], B1[3]};
    const f32x2 bz0 = {B2[0], B2[1]}, bz1 = {B2[2], B2[3]};
    const f32x2 zero = {0.f, 0.f};

    const __bf16* supBase = supb + (size_t)bV * SCOL + c0;

    // ---- Phase N: neighbor max over 2 passes (2 vertices/wave each)
#pragma unroll
    for (int p = 0; p < 2; ++p) {
        const int ul  = p * 8 + wid * 2 + half;      // 0..15
        const int row = bV + u0 + ul;

        const float vx = verts[row * 3 + 0];
        const float vy = verts[row * 3 + 1];
        const float vz = verts[row * 3 + 2];

        int gs[NNB];
        {
            const i32x4* np4 = reinterpret_cast<const i32x4*>(nbr + (size_t)row * NNB);
#pragma unroll
            for (int t = 0; t < 5; ++t) {
                const i32x4 g4 = np4[t];
                gs[t*4+0] = g4[0]; gs[t*4+1] = g4[1]; gs[t*4+2] = g4[2]; gs[t*4+3] = g4[3];
            }
        }

        f32x2 mA0 = {-INFINITY, -INFINITY}, mA1 = mA0, mB0 = mA0, mB1 = mA0;
        float d2max = 0.f;

#pragma unroll
        for (int t = 0; t < 4; ++t) {
            // issue 10 support gathers + 5 vertex reads for 5 neighbors
            u16x4 s0r[5], s1r[5];
            float px[5], py[5], pz[5];
#pragma unroll
            for (int q = 0; q < 5; ++q) {
                const int g = gs[t * 5 + q];
                const __bf16* sg = supBase + (size_t)g * SCOL;
                s0r[q] = *(const u16x4*)(sg);
                s1r[q] = *(const u16x4*)(sg + OUTC);
                const float* vp = verts + (size_t)(bV + g) * 3;
                px[q] = vp[0]; py[q] = vp[1]; pz[q] = vp[2];
            }
#pragma unroll
            for (int q = 0; q < 5; ++q) {
                const float dx = px[q] - vx, dy = py[q] - vy, dz = pz[q] - vz;
                const float d2 = fmaf(dx, dx, fmaf(dy, dy, dz * dz));
                d2max = fmaxf(d2max, d2);
                const float inv = __builtin_amdgcn_rsqf(fmaxf(d2, 1e-24f));  // == 1/max(dist,1e-12)
                const f32x2 nX = {dx * inv, dx * inv};
                const f32x2 nY = {dy * inv, dy * inv};
                const f32x2 nZ = {dz * inv, dz * inv};

                const f32x2 s0lo = {b2f(s0r[q][0]), b2f(s0r[q][1])};
                const f32x2 s0hi = {b2f(s0r[q][2]), b2f(s0r[q][3])};
                const f32x2 s1lo = {b2f(s1r[q][0]), b2f(s1r[q][1])};
                const f32x2 s1hi = {b2f(s1r[q][2]), b2f(s1r[q][3])};

                const f32x2 tA0 = emax(efma(nZ, az0, efma(nY, ay0, nX * ax0)), zero);
                const f32x2 tA1 = emax(efma(nZ, az1, efma(nY, ay1, nX * ax1)), zero);
                const f32x2 tB0 = emax(efma(nZ, bz0, efma(nY, by0, nX * bx0)), zero);
                const f32x2 tB1 = emax(efma(nZ, bz1, efma(nY, by1, nX * bx1)), zero);
                mA0 = emax(mA0, tA0 * s0lo);
                mA1 = emax(mA1, tA1 * s0hi);
                mB0 = emax(mB0, tB0 * s1lo);
                mB1 = emax(mB1, tB1 * s1hi);
            }
        }

        const f32x4 cc = *(const f32x4*)(center + (size_t)row * OUTC + c0);
        const f32x2 f01 = (f32x2){cc[0], cc[1]} + mA0 + mB0;
        const f32x2 f23 = (f32x2){cc[2], cc[3]} + mA1 + mB1;
        bf16x4 fx;
        fx[0] = (__bf16)f01[0]; fx[1] = (__bf16)f01[1];
        fx[2] = (__bf16)f23[0]; fx[3] = (__bf16)f23[1];
        *(bf16x4*)(&Xl[ul][c0]) = fx;
        if (sl == 0) dl[ul] = sqrtf(d2max);
    }
    __syncthreads();

    // ---- Phase G: out = Xl @ Wm1b^T + dmax*w2 + mb (MFMA, K=128)
    // wave wid -> cols wid*32..+31 (2 tiles of 16), rows 0..15.
    {
        const int cb = wid * 32;

        bf16x8 a[4];
#pragma unroll
        for (int kf = 0; kf < 4; ++kf)
            a[kf] = *(const bf16x8*)(&Xl[ln][lg * 8 + kf * 32]);

        f32x4 acc[2];
        acc[0] = (f32x4)0.f; acc[1] = (f32x4)0.f;

        const __bf16* bp = Wm1b + (size_t)(cb + ln) * OUTC + lg * 8;
#pragma unroll
        for (int t = 0; t < 2; ++t) {
#pragma unroll
            for (int kf = 0; kf < 4; ++kf) {
                const bf16x8 b = *(const bf16x8*)(bp + t * 16 * OUTC + kf * 32);
                acc[t] = __builtin_amdgcn_mfma_f32_16x16x32_bf16(a[kf], b, acc[t], 0, 0, 0);
            }
        }

        float dm[4];
#pragma unroll
        for (int r = 0; r < 4; ++r) dm[r] = dl[lg * 4 + r];

        const int rowg0 = bV + u0 + lg * 4;
#pragma unroll
        for (int t = 0; t < 2; ++t) {
            const int col = cb + t * 16 + ln;
            const float w2c = w2[col];
            const float bb  = mb[col];
#pragma unroll
            for (int r = 0; r < 4; ++r)
                out[(size_t)(rowg0 + r) * OUTC + col] = fmaf(dm[r], w2c, acc[t][r] + bb);
        }
    }
}

// ---------------------------------------------------------------------------
extern "C" void kernel_launch(void* const* d_in, const int* in_sizes, int n_in,
                              void* d_out, int out_size, void* d_ws, size_t ws_size,
                              hipStream_t stream) {
    const int*   nbr   = (const int*)  d_in[0];
    const float* verts = (const float*)d_in[1];
    const float* fm    = (const float*)d_in[2];
    const float* W     = (const float*)d_in[3];
    const float* bias  = (const float*)d_in[4];
    const float* dirs  = (const float*)d_in[5];
    const float* dw    = (const float*)d_in[6];
    const float* Wm    = (const float*)d_in[7];
    const float* mb    = (const float*)d_in[8];
    float* out = (float*)d_out;

    // workspace layout (all 16B-aligned)
    float*  center  = (float*)d_ws;                               // 16384*128 f32
    __bf16* supb    = (__bf16*)(center + (size_t)ROWS * OUTC);    // 16384*256 bf16
    __bf16* WTb     = supb + (size_t)ROWS * SCOL;                 // 384*64 bf16
    __bf16* Wm1b    = WTb + NCOL * INC;                           // 128*128 bf16
    float*  w2      = (float*)(Wm1b + OUTC * OUTC);               // 128 f32

    k_prep <<<161,        256, 0, stream>>>(W, Wm, dw, WTb, Wm1b, w2);
    k_feat <<<ROWS / 32,  256, 0, stream>>>(fm, WTb, bias, center, supb);
    k_no   <<<ROWS / 16,  256, 0, stream>>>(nbr, verts, dirs, center, supb, Wm1b, w2, mb, out);
}